// Round 1
// baseline (870.811 us; speedup 1.0000x reference)
//
#include <hip/hip_runtime.h>

#define BN   8
#define TMAX 256
#define UMAX 128
#define U1   129   // U_MAX + 1
#define VV   512
#define SD   392   // padded diagonal count (max s = 383)

// logaddexp for finite inputs
__device__ __forceinline__ float logaddexpf_(float a, float b) {
    float mx = fmaxf(a, b);
    float d  = fabsf(a - b);
    return mx + log1pf(__expf(-d));
}

// One wave (64 lanes) per (b,t,u) row of 512 logits.
// Computes LSE, writes blank logp and emit logp into DIAGONAL-major
// scratch: blankD[b][s=t+u][u], emitD[b][s=t+u][u] so the DP kernel's
// per-diagonal reads are contiguous/coalesced.
__global__ __launch_bounds__(256) void lse_extract(
        const float* __restrict__ logits,
        const int*   __restrict__ y,
        const int*   __restrict__ Tl,
        const int*   __restrict__ Ul,
        float* __restrict__ blankD,
        float* __restrict__ emitD) {
    int lane = threadIdx.x & 63;
    int row  = blockIdx.x * 4 + (threadIdx.x >> 6);
    if (row >= BN * TMAX * U1) return;
    int b   = row / (TMAX * U1);
    int rem = row - b * (TMAX * U1);
    int t   = rem / U1;
    int u   = rem - t * U1;
    // rows beyond this batch's (T_len, U_len) never feed the DP
    if (t >= Tl[b] || u > Ul[b]) return;

    const float4* base = (const float4*)(logits + (size_t)row * VV);
    float4 r0 = base[lane * 2];
    float4 r1 = base[lane * 2 + 1];

    float m = fmaxf(fmaxf(fmaxf(r0.x, r0.y), fmaxf(r0.z, r0.w)),
                    fmaxf(fmaxf(r1.x, r1.y), fmaxf(r1.z, r1.w)));
#pragma unroll
    for (int off = 32; off > 0; off >>= 1) m = fmaxf(m, __shfl_xor(m, off));

    float s = __expf(r0.x - m) + __expf(r0.y - m) + __expf(r0.z - m) + __expf(r0.w - m)
            + __expf(r1.x - m) + __expf(r1.y - m) + __expf(r1.z - m) + __expf(r1.w - m);
#pragma unroll
    for (int off = 32; off > 0; off >>= 1) s += __shfl_xor(s, off);

    float lse = m + __logf(s);
    int sd = t + u;
    if (lane == 0)
        blankD[((size_t)b * SD + sd) * U1 + u] = r0.x - lse;
    if (u < UMAX) {
        int yv = y[b * UMAX + u];           // wave-uniform
        if ((yv >> 3) == lane) {
            int e = yv & 7;
            float v = (e == 0) ? r0.x : (e == 1) ? r0.y : (e == 2) ? r0.z : (e == 3) ? r0.w
                    : (e == 4) ? r1.x : (e == 5) ? r1.y : (e == 6) ? r1.z : r1.w;
            emitD[((size_t)b * SD + sd) * UMAX + u] = v - lse;
        }
    }
}

// Wavefront DP: one block per batch element, thread u owns column u.
// alpha[t,u] = LAE(alpha[t-1,u]+blank[t-1,u], alpha[t,u-1]+emit[t,u-1]).
// Both parents of diagonal d live on diagonal d-1; both needed global
// values live on source-diagonal s = d-1 (contiguous in the diag layout).
__global__ __launch_bounds__(192) void dp_wavefront(
        const float* __restrict__ blankD,
        const float* __restrict__ emitD,
        const int*   __restrict__ Tlp,
        const int*   __restrict__ Ulp,
        float* __restrict__ out) {
    __shared__ float buf[2][U1 + 4];
    int b = blockIdx.x;
    int u = threadIdx.x;
    int Tl = Tlp[b], Ul = Ulp[b];
    int dend = Tl - 1 + Ul;
    const float* bD = blankD + (size_t)b * SD * U1;
    const float* eD = emitD  + (size_t)b * SD * UMAX;
    bool act_u = (u < U1);
    int  ue    = (u == 0) ? 0 : u - 1;

    // depth-2 register prefetch of source diagonals
    float pb[2], pe[2];
    if (act_u) {
        pb[1] = bD[(size_t)0 * U1   + u];   // s=0 -> used at d=1
        pe[1] = eD[(size_t)0 * UMAX + ue];
        pb[0] = bD[(size_t)1 * U1   + u];   // s=1 -> used at d=2
        pe[0] = eD[(size_t)1 * UMAX + ue];
    }
    if (u == 0) buf[0][0] = 0.0f;           // alpha[0,0]
    __syncthreads();

    for (int d = 1; d <= dend; ++d) {
        int par = d & 1;
        int ulo = d - (Tl - 1); if (ulo < 0) ulo = 0;
        int uhi = (d < Ul) ? d : Ul;
        if (act_u && u >= ulo && u <= uhi) {
            float cur;
            if (u == 0) {
                cur = buf[par ^ 1][0] + pb[par];                 // blank-only edge
            } else if (u == d) {
                cur = buf[par ^ 1][u - 1] + pe[par];             // t==0 emit-only edge
            } else {
                float up = buf[par ^ 1][u]     + pb[par];
                float lf = buf[par ^ 1][u - 1] + pe[par];
                cur = logaddexpf_(up, lf);
            }
            buf[par][u] = cur;
            if (d == dend && u == Ul) {
                float lp = cur + bD[(size_t)dend * U1 + Ul];     // + blank[T-1, U]
                atomicAdd(out, -lp * (1.0f / BN));
            }
        }
        if (act_u) {                         // prefetch s = d+1 for step d+2
            pb[par] = bD[(size_t)(d + 1) * U1   + u];
            pe[par] = eD[(size_t)(d + 1) * UMAX + ue];
        }
        __syncthreads();
    }
}

extern "C" void kernel_launch(void* const* d_in, const int* in_sizes, int n_in,
                              void* d_out, int out_size, void* d_ws, size_t ws_size,
                              hipStream_t stream) {
    const float* logits = (const float*)d_in[0];
    const int*   y      = (const int*)d_in[1];
    const int*   Tl     = (const int*)d_in[2];
    const int*   Ul     = (const int*)d_in[3];
    float* out = (float*)d_out;

    float* blankD = (float*)d_ws;                       // 8*392*129 floats
    float* emitD  = blankD + (size_t)BN * SD * U1;      // 8*392*128 floats

    hipMemsetAsync(d_out, 0, sizeof(float), stream);    // out is poisoned pre-launch

    int rows = BN * TMAX * U1;                           // 264192
    lse_extract<<<dim3((rows + 3) / 4), dim3(256), 0, stream>>>(
        logits, y, Tl, Ul, blankD, emitD);
    dp_wavefront<<<dim3(BN), dim3(192), 0, stream>>>(blankD, emitD, Tl, Ul, out);
}